// Round 1
// baseline (356.697 us; speedup 1.0000x reference)
//
#include <hip/hip_runtime.h>

#define DI __device__ __forceinline__

constexpr int Bc = 4, Tc = 4096, Ic = 1024, Ec = 16, Kc = 512, Jc = 1024;

typedef __attribute__((ext_vector_type(8))) short short8;
typedef __attribute__((ext_vector_type(4))) float floatx4;

// pack two fp32 -> two bf16 (round-half-up) in one v_perm after biasing
DI unsigned pack2_bf16(float a, float b) {
  union { float f; unsigned u; } ua, ub;
  ua.f = a; ub.f = b;
  const unsigned x = ua.u + 0x8000u;
  const unsigned y = ub.u + 0x8000u;
#if __has_builtin(__builtin_amdgcn_perm)
  // result bytes (LE): [x2,x3,y2,y3]  => low16 = bf16(a), high16 = bf16(b)
  return __builtin_amdgcn_perm(y, x, 0x07060302u);
#else
  return (x >> 16) | (y & 0xFFFF0000u);
#endif
}

DI void async_load16(const void* g, void* lds) {
  __builtin_amdgcn_global_load_lds((const __attribute__((address_space(1))) void*)g,
                                   (__attribute__((address_space(3))) void*)lds,
                                   16, 0, 0);
}

// W [E][I][J] fp32  ->  Wt [E][J][I] bf16   (transpose + convert)
__global__ __launch_bounds__(256) void transpose_w(const float* __restrict__ W,
                                                   unsigned short* __restrict__ Wt) {
  __shared__ float tile[64][65];
  const int bid = blockIdx.x;
  const int jt = bid & 15;         // J/64
  const int it = (bid >> 4) & 15;  // I/64
  const int e  = bid >> 8;
  const int t  = threadIdx.x;

  const float* Wp = W + ((size_t)e * Ic + (size_t)it * 64) * Jc + jt * 64;
  const int jl  = (t & 15) * 4;
  const int il0 = t >> 4;
#pragma unroll
  for (int p = 0; p < 4; ++p) {
    const int il = p * 16 + il0;
    const float4 v = *(const float4*)(Wp + (size_t)il * Jc + jl);
    tile[il][jl + 0] = v.x; tile[il][jl + 1] = v.y;
    tile[il][jl + 2] = v.z; tile[il][jl + 3] = v.w;
  }
  __syncthreads();
  unsigned short* Wo = Wt + ((size_t)e * Jc + (size_t)jt * 64) * Ic + it * 64;
  const int ilw = (t & 15) * 4;
  const int jl0 = t >> 4;
#pragma unroll
  for (int p = 0; p < 4; ++p) {
    const int jlw = p * 16 + jl0;
    uint2 u;
    u.x = pack2_bf16(tile[ilw + 0][jlw], tile[ilw + 1][jlw]);
    u.y = pack2_bf16(tile[ilw + 2][jlw], tile[ilw + 3][jlw]);
    *(uint2*)(Wo + (size_t)jlw * Ic + ilw) = u;
  }
}

// Y[b,e,k,j] = sum_i bf16(X[b, ind[b,e,k], i]) * bf16(W[e,i,j])
// block tile: 128 (k) x 128 (j), BK=32, 4 waves each 64x64 via 4x4 mfma 16x16x32
__global__ __launch_bounds__(256) void moe_gemm(const float* __restrict__ X,
                                                const int* __restrict__ ind,
                                                const unsigned short* __restrict__ Wt,
                                                float* __restrict__ Y) {
  __shared__ unsigned short As[128 * 32];          // bf16, 8 KB
  __shared__ unsigned short Bs[128 * 32];          // bf16, 8 KB
  __shared__ unsigned long long rowA[128];         // gathered X row byte-addresses

  const int bid = blockIdx.x;
  const int jt = bid & 7;          // J/128
  const int kt = (bid >> 3) & 3;   // K/128
  const int e  = (bid >> 5) & 15;
  const int b  = bid >> 9;

  const int t = threadIdx.x;
  const int w = t >> 6;
  const int l = t & 63;

  if (t < 128) {
    const int r = ind[((b * Ec + e) * Kc) + kt * 128 + t];
    rowA[t] = (unsigned long long)(const void*)X +
              ((unsigned long long)(b * Tc + r) * (unsigned long long)Ic) * 4ull;
  }
  __syncthreads();

  // A staging: thread t loads rows p*32 + (t>>3), floats (t&7)*4 .. +3
  const int c4 = (t & 7) * 4;
  unsigned long long abase[4];
#pragma unroll
  for (int p = 0; p < 4; ++p)
    abase[p] = rowA[p * 32 + (t >> 3)] + (unsigned long long)(c4 * 4);
  unsigned short* awr = &As[(t >> 3) * 32 + c4];   // + p*1024 elements per pass

  // B staging: wave w loads n-row groups rg = 2w, 2w+1; lane l -> n=rg*16+(l>>2), 16B chunk (l&3)
  const unsigned short* bsrc0 =
      Wt + ((size_t)(e * Jc + jt * 128 + (w * 2 + 0) * 16 + (l >> 2))) * Ic + (l & 3) * 8;
  const unsigned short* bsrc1 =
      Wt + ((size_t)(e * Jc + jt * 128 + (w * 2 + 1) * 16 + (l >> 2))) * Ic + (l & 3) * 8;
  unsigned short* bdst0 = &Bs[(w * 2 + 0) * 16 * 32];  // wave-uniform; HW adds lane*16B
  unsigned short* bdst1 = &Bs[(w * 2 + 1) * 16 * 32];

  floatx4 acc[4][4];
#pragma unroll
  for (int tm = 0; tm < 4; ++tm)
#pragma unroll
    for (int tn = 0; tn < 4; ++tn) acc[tm][tn] = (floatx4){0.f, 0.f, 0.f, 0.f};

  const int wm = (w & 1) * 64;
  const int wn = (w >> 1) * 64;
  const int lrow = l & 15;
  const int quad = l >> 4;

  for (int kk = 0; kk < Ic / 32; ++kk) {
    // global A loads (no LDS touch) - overlap with previous iter's tail
    float4 av[4];
#pragma unroll
    for (int p = 0; p < 4; ++p)
      av[p] = *reinterpret_cast<const float4*>(abase[p] + (unsigned long long)(kk * 128));

    __syncthreads();  // previous iter done reading LDS

    async_load16(bsrc0 + kk * 32, bdst0);
    async_load16(bsrc1 + kk * 32, bdst1);

#pragma unroll
    for (int p = 0; p < 4; ++p) {
      uint2 u;
      u.x = pack2_bf16(av[p].x, av[p].y);
      u.y = pack2_bf16(av[p].z, av[p].w);
      *(uint2*)(awr + p * 1024) = u;
    }
    __syncthreads();  // drains vmcnt (global_load_lds) + lgkm (ds_write)

    short8 af[4], bf[4];
#pragma unroll
    for (int tm = 0; tm < 4; ++tm)
      af[tm] = *(const short8*)&As[(wm + tm * 16 + lrow) * 32 + quad * 8];
#pragma unroll
    for (int tn = 0; tn < 4; ++tn)
      bf[tn] = *(const short8*)&Bs[(wn + tn * 16 + lrow) * 32 + quad * 8];
#pragma unroll
    for (int tm = 0; tm < 4; ++tm)
#pragma unroll
      for (int tn = 0; tn < 4; ++tn)
        acc[tm][tn] = __builtin_amdgcn_mfma_f32_16x16x32_bf16(af[tm], bf[tn], acc[tm][tn], 0, 0, 0);
  }

  // C/D layout: col = lane&15, row = quad*4 + reg
  float* Yp = Y + ((size_t)(b * Ec + e) * Kc + (size_t)kt * 128) * Jc + jt * 128;
#pragma unroll
  for (int tm = 0; tm < 4; ++tm) {
#pragma unroll
    for (int tn = 0; tn < 4; ++tn) {
#pragma unroll
      for (int r = 0; r < 4; ++r) {
        const int row = wm + tm * 16 + quad * 4 + r;
        const int col = wn + tn * 16 + lrow;
        Yp[(size_t)row * Jc + col] = acc[tm][tn][r];
      }
    }
  }
}

extern "C" void kernel_launch(void* const* d_in, const int* in_sizes, int n_in,
                              void* d_out, int out_size, void* d_ws, size_t ws_size,
                              hipStream_t stream) {
  const float* X = (const float*)d_in[0];
  const int* ind = (const int*)d_in[1];
  const float* W = (const float*)d_in[2];
  float* Y = (float*)d_out;
  unsigned short* Wt = (unsigned short*)d_ws;  // E*J*I bf16 = 33.5 MB

  hipLaunchKernelGGL(transpose_w, dim3(Ec * 16 * 16), dim3(256), 0, stream, W, Wt);
  hipLaunchKernelGGL(moe_gemm, dim3(Bc * Ec * 4 * 8), dim3(256), 0, stream, X, ind, Wt, Y);
}

// Round 2
// 355.711 us; speedup vs baseline: 1.0028x; 1.0028x over previous
//
#include <hip/hip_runtime.h>

#define DI __device__ __forceinline__

constexpr int Bc = 4, Tc = 4096, Ic = 1024, Ec = 16, Kc = 512, Jc = 1024;

typedef __attribute__((ext_vector_type(8))) short short8;
typedef __attribute__((ext_vector_type(4))) float floatx4;

// pack two fp32 -> two bf16 (round-half-up): low16 = bf16(a), high16 = bf16(b)
DI unsigned pack2_bf16(float a, float b) {
  union { float f; unsigned u; } ua, ub;
  ua.f = a; ub.f = b;
  const unsigned x = ua.u + 0x8000u;
  const unsigned y = ub.u + 0x8000u;
#if __has_builtin(__builtin_amdgcn_perm)
  return __builtin_amdgcn_perm(y, x, 0x07060302u);
#else
  return (x >> 16) | (y & 0xFFFF0000u);
#endif
}

DI void async_load16(const void* g, void* lds) {
  __builtin_amdgcn_global_load_lds((const __attribute__((address_space(1))) void*)g,
                                   (__attribute__((address_space(3))) void*)lds,
                                   16, 0, 0);
}

// ---------------------------------------------------------------------------
// Xg[row][i] = bf16(X[b, ind[row], i]), row = (b*E + e)*K + k.  One row/block.
__global__ __launch_bounds__(256) void gather_cast(const float* __restrict__ X,
                                                   const int* __restrict__ ind,
                                                   unsigned short* __restrict__ Xg) {
  const int row = blockIdx.x;            // 0 .. B*E*K-1 (32768)
  const int t = threadIdx.x;
  const int b = row >> 13;               // E*K = 8192 rows per batch
  const int r = ind[row];
  const float4 v = *(const float4*)(X + ((size_t)(b * Tc + r)) * Ic + t * 4);
  uint2 u;
  u.x = pack2_bf16(v.x, v.y);
  u.y = pack2_bf16(v.z, v.w);
  *(uint2*)(Xg + (size_t)row * Ic + t * 4) = u;
}

// ---------------------------------------------------------------------------
// W [E][I][J] fp32 -> Wt tiled bf16: chunk((e*8+jt)*32 + kk) = [n:128][i:32],
// i.e. Wt[chunk][n][il] = bf16(W[e][kk*32+il][jt*128+n]).  8 KB per chunk.
__global__ __launch_bounds__(256) void transpose_w(const float* __restrict__ W,
                                                   unsigned short* __restrict__ Wt) {
  __shared__ float tile[32][129];        // +1 pad: column reads conflict-free
  const int bid = blockIdx.x;            // e(16) x jt(8) x kk(32) = 4096
  const int kk = bid & 31;
  const int jt = (bid >> 5) & 7;
  const int e  = bid >> 8;
  const int t  = threadIdx.x;

  const float* Wp = W + ((size_t)(e * Ic + kk * 32)) * Jc + jt * 128;
#pragma unroll
  for (int p = 0; p < 4; ++p) {
    const int il = p * 8 + (t >> 5);     // 0..31
    const int c4 = (t & 31) * 4;         // 0..124
    const float4 v = *(const float4*)(Wp + (size_t)il * Jc + c4);
    tile[il][c4 + 0] = v.x; tile[il][c4 + 1] = v.y;
    tile[il][c4 + 2] = v.z; tile[il][c4 + 3] = v.w;
  }
  __syncthreads();

  unsigned short* out = Wt + ((size_t)((e * 8 + jt) * 32 + kk)) * 4096;
#pragma unroll
  for (int h = 0; h < 2; ++h) {
    const int n   = h * 64 + (t >> 2);
    const int il0 = (t & 3) * 8;
    unsigned u[4];
#pragma unroll
    for (int q = 0; q < 4; ++q)
      u[q] = pack2_bf16(tile[il0 + 2 * q][n], tile[il0 + 2 * q + 1][n]);
    *(uint4*)(out + (size_t)(h * 256 + t) * 8) = *(uint4*)u;
  }
}

// ---------------------------------------------------------------------------
// Y[b,e,k,j] = sum_i Xg[(b,e,k)][i] * Wt[e][i][j]   (both bf16, fp32 acc)
// block tile 128(k) x 128(j), BK=32, 4 waves of 64x64 (4x4 mfma 16x16x32).
// Both operands staged via global_load_lds width=16 (m97 structure), with
// XOR chunk swizzle (phys_chunk = logical_chunk ^ (n&3)) applied at the
// global source so b128 fragment reads spread across all bank-phase slots.
__global__ __launch_bounds__(256) void moe_gemm(const unsigned short* __restrict__ Xg,
                                                const unsigned short* __restrict__ Wt,
                                                float* __restrict__ Y) {
  __shared__ unsigned short As[128 * 32];   // 8 KB
  __shared__ unsigned short Bs[128 * 32];   // 8 KB

  const int bid = blockIdx.x;
  const int jt = bid & 7;
  const int kt = (bid >> 3) & 3;
  const int e  = (bid >> 5) & 15;
  const int b  = bid >> 9;

  const int t = threadIdx.x;
  const int w = t >> 6;
  const int l = t & 63;
  const int nl  = l >> 2;                 // row within 16-row pass
  const int csw = (l & 3) ^ (nl & 3);     // swizzled source chunk

  // A: rows R0 + (w*2+p)*16 + nl of Xg; 16B chunk csw within kk's 64B window
  const int R0 = (b * Ec + e) * Kc + kt * 128;
  const unsigned short* asrc[2];
  const unsigned short* bsrc[2];
  unsigned short* adst[2];
  unsigned short* bdst[2];
#pragma unroll
  for (int p = 0; p < 2; ++p) {
    const int rg = w * 2 + p;             // 16-row group 0..7
    asrc[p] = Xg + (size_t)(R0 + rg * 16 + nl) * Ic + csw * 8;
    bsrc[p] = Wt + ((size_t)((e * 8 + jt) * 32)) * 4096 + rg * 512 + nl * 32 + csw * 8;
    adst[p] = &As[rg * 512];              // wave-uniform; HW adds lane*16B
    bdst[p] = &Bs[rg * 512];
  }

  floatx4 acc[4][4];
#pragma unroll
  for (int tm = 0; tm < 4; ++tm)
#pragma unroll
    for (int tn = 0; tn < 4; ++tn) acc[tm][tn] = (floatx4){0.f, 0.f, 0.f, 0.f};

  const int wm = (w & 1) * 64;
  const int wn = (w >> 1) * 64;
  const int lrow = l & 15;
  const int quad = l >> 4;
  const int swz  = lrow & 3;              // consumer-side chunk swizzle

  for (int kk = 0; kk < Ic / 32; ++kk) {
    __syncthreads();                      // prior iter's LDS reads done
#pragma unroll
    for (int p = 0; p < 2; ++p) {
      async_load16(asrc[p] + kk * 32, adst[p]);
      async_load16(bsrc[p] + (size_t)kk * 4096, bdst[p]);
    }
    __syncthreads();                      // drains vmcnt -> LDS tiles ready

    short8 af[4], bf[4];
#pragma unroll
    for (int tm = 0; tm < 4; ++tm)
      af[tm] = *(const short8*)&As[(wm + tm * 16 + lrow) * 32 + (quad ^ swz) * 8];
#pragma unroll
    for (int tn = 0; tn < 4; ++tn)
      bf[tn] = *(const short8*)&Bs[(wn + tn * 16 + lrow) * 32 + (quad ^ swz) * 8];
#pragma unroll
    for (int tm = 0; tm < 4; ++tm)
#pragma unroll
      for (int tn = 0; tn < 4; ++tn)
        acc[tm][tn] = __builtin_amdgcn_mfma_f32_16x16x32_bf16(af[tm], bf[tn], acc[tm][tn], 0, 0, 0);
  }

  // C/D layout: col = lane&15, row = quad*4 + reg
  float* Yp = Y + ((size_t)(b * Ec + e) * Kc + (size_t)kt * 128) * Jc + jt * 128;
#pragma unroll
  for (int tm = 0; tm < 4; ++tm) {
#pragma unroll
    for (int tn = 0; tn < 4; ++tn) {
#pragma unroll
      for (int r = 0; r < 4; ++r) {
        const int row = wm + tm * 16 + quad * 4 + r;
        const int col = wn + tn * 16 + lrow;
        Yp[(size_t)row * Jc + col] = acc[tm][tn][r];
      }
    }
  }
}

extern "C" void kernel_launch(void* const* d_in, const int* in_sizes, int n_in,
                              void* d_out, int out_size, void* d_ws, size_t ws_size,
                              hipStream_t stream) {
  const float* X = (const float*)d_in[0];
  const int* ind = (const int*)d_in[1];
  const float* W = (const float*)d_in[2];
  float* Y = (float*)d_out;

  unsigned short* Xg = (unsigned short*)d_ws;                       // 64 MiB
  unsigned short* Wt = (unsigned short*)d_ws + (size_t)Bc * Ec * Kc * Ic;  // 32 MiB

  hipLaunchKernelGGL(gather_cast, dim3(Bc * Ec * Kc), dim3(256), 0, stream, X, ind, Xg);
  hipLaunchKernelGGL(transpose_w, dim3(Ec * 8 * 32), dim3(256), 0, stream, W, Wt);
  hipLaunchKernelGGL(moe_gemm, dim3(Bc * Ec * 4 * 8), dim3(256), 0, stream, Xg, Wt, Y);
}

// Round 3
// 350.116 us; speedup vs baseline: 1.0188x; 1.0160x over previous
//
#include <hip/hip_runtime.h>

#define DI __device__ __forceinline__

constexpr int Bc = 4, Tc = 4096, Ic = 1024, Ec = 16, Kc = 512, Jc = 1024;

typedef __attribute__((ext_vector_type(8))) short short8;
typedef __attribute__((ext_vector_type(4))) float floatx4;

// pack two fp32 -> two bf16 (round-half-up): low16 = bf16(a), high16 = bf16(b)
DI unsigned pack2_bf16(float a, float b) {
  union { float f; unsigned u; } ua, ub;
  ua.f = a; ub.f = b;
  const unsigned x = ua.u + 0x8000u;
  const unsigned y = ub.u + 0x8000u;
#if __has_builtin(__builtin_amdgcn_perm)
  return __builtin_amdgcn_perm(y, x, 0x07060302u);
#else
  return (x >> 16) | (y & 0xFFFF0000u);
#endif
}

DI void async_load16(const void* g, void* lds) {
  __builtin_amdgcn_global_load_lds((const __attribute__((address_space(1))) void*)g,
                                   (__attribute__((address_space(3))) void*)lds,
                                   16, 0, 0);
}

// ---------------------------------------------------------------------------
// Fused prep. Even blocks: gather+cast X into tiled Xg[tile][kk][128][32].
// Odd blocks: transpose+cast W into tiled Wt[(e*8+jt)*32+kk][128n][32i].
__global__ __launch_bounds__(256) void prep(const float* __restrict__ X,
                                            const int* __restrict__ ind,
                                            const float* __restrict__ W,
                                            unsigned short* __restrict__ Xg,
                                            unsigned short* __restrict__ Wt) {
  __shared__ __align__(16) char smem[32 * 260 * 2];  // 16.6 KB, aliased by both parts
  const int bid = blockIdx.x >> 1;
  const int t = threadIdx.x;

  if ((blockIdx.x & 1) == 0) {
    // ---- X part: 8 rows per block (4096 blocks) ----
    unsigned short* Ls = (unsigned short*)smem;       // [kk][260]: g*32 within, pitch 260
    const int g = t >> 5, kk = t & 31;
    const int R = bid * 8 + g;                        // global gathered-row id
    const int b = R >> 13;                            // E*K = 8192 rows per batch
    const int xr = ind[R];
    const float* src = X + ((size_t)(b * Tc + xr)) * Ic + kk * 32;
    unsigned u[16];
#pragma unroll
    for (int q = 0; q < 8; ++q) {
      const float4 v = *(const float4*)(src + q * 4);
      u[2 * q]     = pack2_bf16(v.x, v.y);
      u[2 * q + 1] = pack2_bf16(v.z, v.w);
    }
    unsigned short* lp = &Ls[kk * 260 + g * 32];
#pragma unroll
    for (int q = 0; q < 4; ++q) *(uint4*)(lp + q * 8) = *(uint4*)&u[4 * q];
    __syncthreads();
    // write: lanes 0..7 cover consecutive rows -> 512B contiguous per 8 lanes
    const int kk2 = t >> 3, rw = t & 7;
    const int tt = bid >> 4;                          // tile = row/128
    const int rl0 = (bid & 15) * 8;
    unsigned short* dst = Xg + ((size_t)(tt * 32 + kk2) * 128 + rl0 + rw) * 32;
    const unsigned short* lr = &Ls[kk2 * 260 + rw * 32];
#pragma unroll
    for (int q = 0; q < 4; ++q) *(uint4*)(dst + q * 8) = *(const uint4*)(lr + q * 8);
  } else {
    // ---- W part: e(16) x jt(8) x kk(32) = 4096 blocks ----
    float (*tile)[129] = (float(*)[129])smem;         // [32][129] fp32, 16.5 KB
    const int kk = bid & 31;
    const int jt = (bid >> 5) & 7;
    const int e  = bid >> 8;
    const float* Wp = W + ((size_t)(e * Ic + kk * 32)) * Jc + jt * 128;
#pragma unroll
    for (int p = 0; p < 4; ++p) {
      const int il = p * 8 + (t >> 5);
      const int c4 = (t & 31) * 4;
      const float4 v = *(const float4*)(Wp + (size_t)il * Jc + c4);
      tile[il][c4 + 0] = v.x; tile[il][c4 + 1] = v.y;
      tile[il][c4 + 2] = v.z; tile[il][c4 + 3] = v.w;
    }
    __syncthreads();
    unsigned short* out = Wt + ((size_t)((e * 8 + jt) * 32 + kk)) * 4096;
#pragma unroll
    for (int h = 0; h < 2; ++h) {
      const int n   = h * 64 + (t >> 2);
      const int il0 = (t & 3) * 8;
      unsigned u[4];
#pragma unroll
      for (int q = 0; q < 4; ++q)
        u[q] = pack2_bf16(tile[il0 + 2 * q][n], tile[il0 + 2 * q + 1][n]);
      *(uint4*)(out + (size_t)(h * 256 + t) * 8) = *(uint4*)u;
    }
  }
}

// ---------------------------------------------------------------------------
// Y[b,e,k,j] = sum_i Xg[.] * Wt[.]  (bf16 in, fp32 acc/out)
// 128(k) x 128(j) tile, BK=64 (two 32-chunks per iter), 4 waves of 64x64.
// Both operands via global_load_lds w16 from tiled sources (1KB/instr streams).
// bid = jt*256 + (b*64 + e*4 + kt): jt-siblings share XCD (Xg L2 reuse),
// same-XCD neighbors cycle e with fixed jt (2MB Wt working set fits L2).
__global__ __launch_bounds__(256) void moe_gemm(const unsigned short* __restrict__ Xg,
                                                const unsigned short* __restrict__ Wt,
                                                float* __restrict__ Y) {
  __shared__ unsigned short As[2 * 128 * 32];   // 16 KB
  __shared__ unsigned short Bs[2 * 128 * 32];   // 16 KB

  const int bid = blockIdx.x;
  const int jt = bid >> 8;
  const int rr = bid & 255;
  const int b  = rr >> 6;
  const int e  = (rr >> 2) & 15;
  const int kt = rr & 3;

  const int t = threadIdx.x;
  const int w = t >> 6;
  const int l = t & 63;
  const int nl  = l >> 2;
  const int csw = (l & 3) ^ (nl & 3);           // source-side chunk swizzle

  const int atile = (b * Ec + e) * 4 + kt;      // global row-tile index
  const unsigned short* abase = Xg + (size_t)atile * 32 * 4096;
  const unsigned short* bbase = Wt + (size_t)((e * 8 + jt) * 32) * 4096;

  // per-(p) invariant offsets: rg = w*2+p, lane offset within an 8KB chunk
  int loff[2];
  unsigned short *adst[2], *bdst[2];
#pragma unroll
  for (int p = 0; p < 2; ++p) {
    const int rg = w * 2 + p;
    loff[p] = (rg * 16 + nl) * 32 + csw * 8;
    adst[p] = &As[rg * 512];                    // wave-uniform; HW adds lane*16B
    bdst[p] = &Bs[rg * 512];
  }

  floatx4 acc[4][4];
#pragma unroll
  for (int tm = 0; tm < 4; ++tm)
#pragma unroll
    for (int tn = 0; tn < 4; ++tn) acc[tm][tn] = (floatx4){0.f, 0.f, 0.f, 0.f};

  const int wm = (w & 1) * 64;
  const int wn = (w >> 1) * 64;
  const int lrow = l & 15;
  const int quad = l >> 4;
  const int swz  = lrow & 3;

  for (int kk2 = 0; kk2 < 16; ++kk2) {
    __syncthreads();                            // prior iter's LDS reads done
#pragma unroll
    for (int s = 0; s < 2; ++s) {
      const size_t cb = (size_t)(kk2 * 2 + s) * 4096;
#pragma unroll
      for (int p = 0; p < 2; ++p) {
        async_load16(abase + cb + loff[p], adst[p] + s * 4096);
        async_load16(bbase + cb + loff[p], bdst[p] + s * 4096);
      }
    }
    __syncthreads();                            // drains vmcnt -> tiles ready

#pragma unroll
    for (int s = 0; s < 2; ++s) {
      short8 af[4], bf[4];
#pragma unroll
      for (int tm = 0; tm < 4; ++tm)
        af[tm] = *(const short8*)&As[s * 4096 + (wm + tm * 16 + lrow) * 32 + (quad ^ swz) * 8];
#pragma unroll
      for (int tn = 0; tn < 4; ++tn)
        bf[tn] = *(const short8*)&Bs[s * 4096 + (wn + tn * 16 + lrow) * 32 + (quad ^ swz) * 8];
#pragma unroll
      for (int tm = 0; tm < 4; ++tm)
#pragma unroll
        for (int tn = 0; tn < 4; ++tn)
          acc[tm][tn] = __builtin_amdgcn_mfma_f32_16x16x32_bf16(af[tm], bf[tn], acc[tm][tn], 0, 0, 0);
    }
  }

  // C/D layout: col = lane&15, row = quad*4 + reg
  float* Yp = Y + ((size_t)(b * Ec + e) * Kc + (size_t)kt * 128) * Jc + jt * 128;
#pragma unroll
  for (int tm = 0; tm < 4; ++tm) {
#pragma unroll
    for (int tn = 0; tn < 4; ++tn) {
#pragma unroll
      for (int r = 0; r < 4; ++r) {
        const int row = wm + tm * 16 + quad * 4 + r;
        const int col = wn + tn * 16 + lrow;
        Yp[(size_t)row * Jc + col] = acc[tm][tn][r];
      }
    }
  }
}

extern "C" void kernel_launch(void* const* d_in, const int* in_sizes, int n_in,
                              void* d_out, int out_size, void* d_ws, size_t ws_size,
                              hipStream_t stream) {
  const float* X = (const float*)d_in[0];
  const int* ind = (const int*)d_in[1];
  const float* W = (const float*)d_in[2];
  float* Y = (float*)d_out;

  unsigned short* Xg = (unsigned short*)d_ws;                              // 64 MiB
  unsigned short* Wt = (unsigned short*)d_ws + (size_t)Bc * Ec * Kc * Ic;  // 32 MiB

  hipLaunchKernelGGL(prep, dim3(8192), dim3(256), 0, stream, X, ind, W, Xg, Wt);
  hipLaunchKernelGGL(moe_gemm, dim3(Bc * Ec * 4 * 8), dim3(256), 0, stream, Xg, Wt, Y);
}